// Round 8
// baseline (1417.281 us; speedup 1.0000x reference)
//
#include <hip/hip_runtime.h>

#define H 256
#define LDK 40  // padded k-stride (halves): 80B rows -> <=2-way LDS bank aliasing (free)

typedef __attribute__((ext_vector_type(8))) short bf16x8;
typedef __attribute__((ext_vector_type(4))) float f32x4;

__device__ __forceinline__ float b2f(ushort h) {
    return __uint_as_float(((unsigned)h) << 16);
}
__device__ __forceinline__ ushort f2bf(float f) {
    unsigned u = __float_as_uint(f);
    unsigned r = (u + 0x7FFF + ((u >> 16) & 1)) >> 16;  // RNE
    return (ushort)r;
}

// ---------------- CSR build ----------------
__global__ __launch_bounds__(256) void k_zero2_i(int* p, int* q, int n) {
    int i = blockIdx.x * 256 + threadIdx.x;
    if (i < n) { p[i] = 0; q[i] = 0; }
}

__global__ __launch_bounds__(256) void k_zero_f(float* p, int n) {
    int i = blockIdx.x * 256 + threadIdx.x;
    if (i < n) p[i] = 0.f;
}

__global__ __launch_bounds__(256) void k_count_deg_i(const int* __restrict__ dst, int* cnt, int E) {
    int i = blockIdx.x * 256 + threadIdx.x;
    if (i < E) atomicAdd(&cnt[dst[i]], 1);
}

__global__ __launch_bounds__(256) void k_scan1(const int* __restrict__ cnt, int* __restrict__ partial,
                                               int* __restrict__ bsums, int N) {
    __shared__ int s[256];
    int t = threadIdx.x;
    int idx = blockIdx.x * 256 + t;
    int v = idx < N ? cnt[idx] : 0;
    s[t] = v;
    __syncthreads();
    for (int off = 1; off < 256; off <<= 1) {
        int add = (t >= off) ? s[t - off] : 0;
        __syncthreads();
        s[t] += add;
        __syncthreads();
    }
    if (idx < N) partial[idx] = s[t];
    if (t == 255) bsums[blockIdx.x] = s[t];
}

__global__ __launch_bounds__(1024) void k_scan2(int* bsums, int nb) {
    __shared__ int s[1024];
    int t = threadIdx.x;
    s[t] = (t < nb) ? bsums[t] : 0;
    __syncthreads();
    for (int off = 1; off < 1024; off <<= 1) {
        int add = (t >= off) ? s[t - off] : 0;
        __syncthreads();
        s[t] += add;
        __syncthreads();
    }
    if (t < nb) bsums[t] = s[t];
}

// rowptr + dinv/selfw in one pass
__global__ __launch_bounds__(256) void k_scan3(const int* __restrict__ partial, const int* __restrict__ bsums,
                                               const int* __restrict__ cnt,
                                               int* __restrict__ rowptr, float* __restrict__ dinv,
                                               float* __restrict__ selfw, int N) {
    int idx = blockIdx.x * 256 + threadIdx.x;
    if (idx < N) {
        int off = blockIdx.x > 0 ? bsums[blockIdx.x - 1] : 0;
        rowptr[idx + 1] = partial[idx] + off;
        if (idx == 0) rowptr[0] = 0;
        float d = 1.0f + (float)cnt[idx];
        dinv[idx] = rsqrtf(d);
        selfw[idx] = 1.0f / d;
    }
}

__global__ __launch_bounds__(256) void k_scatter(const int* __restrict__ src, const int* __restrict__ dst,
                                                 const float* __restrict__ dinv, const int* __restrict__ rowptr,
                                                 int* __restrict__ fill, int* __restrict__ esrc,
                                                 float* __restrict__ ewt, int E) {
    int e = blockIdx.x * 256 + threadIdx.x;
    if (e >= E) return;
    int s = src[e], d = dst[e];
    int pos = rowptr[d] + atomicAdd(&fill[d], 1);
    esrc[pos] = s;
    ewt[pos] = dinv[s] * dinv[d];
}

// ---------------- batched conversions: x->bf16 + all 8 weight transposes ----------------
__device__ __forceinline__ void tcvt_one(long i, const float* __restrict__ W, ushort* __restrict__ Wt,
                                         int K, int M) {
    int k = (int)(i / M), m = (int)(i - (long)k * M);
    Wt[(size_t)m * K + k] = f2bf(W[(size_t)k * M + m]);
}

__global__ __launch_bounds__(256) void k_prep(
    const float* __restrict__ x, ushort* __restrict__ xh, long nx, int DIN,
    const float* __restrict__ Wc1, ushort* Wc1t, const float* __restrict__ Wd1, ushort* Wd1t,
    const float* __restrict__ Wc2, ushort* Wc2t, const float* __restrict__ Wd2, ushort* Wd2t,
    const float* __restrict__ Wc3, ushort* Wc3t, const float* __restrict__ Wd3, ushort* Wd3t,
    const float* __restrict__ Wp1, ushort* Wp1t, const float* __restrict__ Wp2, ushort* Wp2t) {
    long i = (long)blockIdx.x * 256 + threadIdx.x;
    if (i < nx) { xh[i] = f2bf(x[i]); return; }
    i -= nx;
    long n1 = (long)DIN * 256;
    if (i < n1) { tcvt_one(i, Wc1, Wc1t, DIN, 256); return; }
    i -= n1;
    if (i < n1) { tcvt_one(i, Wd1, Wd1t, DIN, 256); return; }
    i -= n1;
    if (i < 65536) { tcvt_one(i, Wc2, Wc2t, 256, 256); return; }
    i -= 65536;
    if (i < 65536) { tcvt_one(i, Wd2, Wd2t, 256, 256); return; }
    i -= 65536;
    if (i < 65536) { tcvt_one(i, Wc3, Wc3t, 256, 256); return; }
    i -= 65536;
    if (i < 65536) { tcvt_one(i, Wd3, Wd3t, 256, 256); return; }
    i -= 65536;
    if (i < 32768) { tcvt_one(i, Wp1, Wp1t, 256, 128); return; }
    i -= 32768;
    if (i < 32768) { tcvt_one(i, Wp2, Wp2t, 128, 256); return; }
}

// ---------------- CSR gather (bf16 in, fp32 acc, bf16 out) ----------------
__global__ __launch_bounds__(256) void k_gather_b4(const ushort* __restrict__ xin, const int* __restrict__ rowptr,
                                                   const int* __restrict__ esrc, const float* __restrict__ ewt,
                                                   const float* __restrict__ selfw, ushort* __restrict__ p,
                                                   int N, int SX, int SP) {
    int node = blockIdx.x * 4 + (threadIdx.x >> 6);
    if (node >= N) return;
    int c = (threadIdx.x & 63) << 2;
    ushort4 h = *(const ushort4*)(xin + (size_t)node * SX + c);
    float sw = selfw[node];
    float a0 = b2f(h.x) * sw, a1 = b2f(h.y) * sw, a2 = b2f(h.z) * sw, a3 = b2f(h.w) * sw;
    int j = rowptr[node], r1 = rowptr[node + 1];
    for (; j + 3 < r1; j += 4) {
        int s0 = esrc[j], s1 = esrc[j + 1], s2 = esrc[j + 2], s3 = esrc[j + 3];
        float w0 = ewt[j], w1 = ewt[j + 1], w2 = ewt[j + 2], w3 = ewt[j + 3];
        ushort4 v0 = *(const ushort4*)(xin + (size_t)s0 * SX + c);
        ushort4 v1 = *(const ushort4*)(xin + (size_t)s1 * SX + c);
        ushort4 v2 = *(const ushort4*)(xin + (size_t)s2 * SX + c);
        ushort4 v3 = *(const ushort4*)(xin + (size_t)s3 * SX + c);
        a0 += b2f(v0.x) * w0 + b2f(v1.x) * w1 + b2f(v2.x) * w2 + b2f(v3.x) * w3;
        a1 += b2f(v0.y) * w0 + b2f(v1.y) * w1 + b2f(v2.y) * w2 + b2f(v3.y) * w3;
        a2 += b2f(v0.z) * w0 + b2f(v1.z) * w1 + b2f(v2.z) * w2 + b2f(v3.z) * w3;
        a3 += b2f(v0.w) * w0 + b2f(v1.w) * w1 + b2f(v2.w) * w2 + b2f(v3.w) * w3;
    }
    for (; j < r1; ++j) {
        int s0 = esrc[j];
        float w0 = ewt[j];
        ushort4 v0 = *(const ushort4*)(xin + (size_t)s0 * SX + c);
        a0 += b2f(v0.x) * w0; a1 += b2f(v0.y) * w0; a2 += b2f(v0.z) * w0; a3 += b2f(v0.w) * w0;
    }
    ushort4 o;
    o.x = f2bf(a0); o.y = f2bf(a1); o.z = f2bf(a2); o.w = f2bf(a3);
    *(ushort4*)(p + (size_t)node * SP + c) = o;
}

__global__ __launch_bounds__(256) void k_gather_b2(const ushort* __restrict__ xin, const int* __restrict__ rowptr,
                                                   const int* __restrict__ esrc, const float* __restrict__ ewt,
                                                   const float* __restrict__ selfw, ushort* __restrict__ p,
                                                   int N, int SX, int SP) {
    int node = blockIdx.x * 4 + (threadIdx.x >> 6);
    if (node >= N) return;
    int c = (threadIdx.x & 63) << 1;
    ushort2 h = *(const ushort2*)(xin + (size_t)node * SX + c);
    float sw = selfw[node];
    float a0 = b2f(h.x) * sw, a1 = b2f(h.y) * sw;
    int j = rowptr[node], r1 = rowptr[node + 1];
    for (; j + 3 < r1; j += 4) {
        int s0 = esrc[j], s1 = esrc[j + 1], s2 = esrc[j + 2], s3 = esrc[j + 3];
        float w0 = ewt[j], w1 = ewt[j + 1], w2 = ewt[j + 2], w3 = ewt[j + 3];
        ushort2 v0 = *(const ushort2*)(xin + (size_t)s0 * SX + c);
        ushort2 v1 = *(const ushort2*)(xin + (size_t)s1 * SX + c);
        ushort2 v2 = *(const ushort2*)(xin + (size_t)s2 * SX + c);
        ushort2 v3 = *(const ushort2*)(xin + (size_t)s3 * SX + c);
        a0 += b2f(v0.x) * w0 + b2f(v1.x) * w1 + b2f(v2.x) * w2 + b2f(v3.x) * w3;
        a1 += b2f(v0.y) * w0 + b2f(v1.y) * w1 + b2f(v2.y) * w2 + b2f(v3.y) * w3;
    }
    for (; j < r1; ++j) {
        int s0 = esrc[j];
        float w0 = ewt[j];
        ushort2 v0 = *(const ushort2*)(xin + (size_t)s0 * SX + c);
        a0 += b2f(v0.x) * w0; a1 += b2f(v0.y) * w0;
    }
    ushort2 o;
    o.x = f2bf(a0); o.y = f2bf(a1);
    *(ushort2*)(p + (size_t)node * SP + c) = o;
}

// ---------------- fused dual-GEMM MFMA:  Out = relu(Pm@Wc + bc) + X@Wd + bd ----------------
// 128 rows x 256 cols per block, 512 threads = 8 waves (2 row-halves x 4 col-quarters).
// W staging (40KB/K-step) amortized over 2x rows vs the 64-row tile.
__global__ __launch_bounds__(512, 4) void k_fused_mfma(
    const ushort* __restrict__ Pm, const ushort* __restrict__ X,
    const ushort* __restrict__ Wct, const ushort* __restrict__ Wdt,
    const float* __restrict__ bc, const float* __restrict__ bd,
    ushort* __restrict__ Out, int N, int K, int SP, int SX) {
    __shared__ short Ps[128 * LDK];
    __shared__ short Xs[128 * LDK];
    __shared__ short Wcs[256 * LDK];
    __shared__ short Wds[256 * LDK];
    const int tid = threadIdx.x;
    const int wave = tid >> 6, lane = tid & 63;
    const int rh = wave >> 2, cq = wave & 3;
    const int row0 = blockIdx.x * 128;

    f32x4 accC[4][4], accD[4][4];
#pragma unroll
    for (int i = 0; i < 4; ++i)
#pragma unroll
        for (int j = 0; j < 4; ++j) { accC[i][j] = (f32x4)0.f; accD[i][j] = (f32x4)0.f; }

    const int sr = tid >> 2, sc = (tid & 3) * 8;  // A staging: 128 rows x 4 quads
    int grow = row0 + sr; if (grow > N - 1) grow = N - 1;
    const int m = lane & 15, kh = (lane >> 4) * 8;

    for (int k0 = 0; k0 < K; k0 += 32) {
        *(uint4*)&Ps[sr * LDK + sc] = *(const uint4*)(Pm + (size_t)grow * SP + k0 + sc);
        *(uint4*)&Xs[sr * LDK + sc] = *(const uint4*)(X + (size_t)grow * SX + k0 + sc);
#pragma unroll
        for (int p = 0; p < 2; ++p) {
            int col = p * 128 + (tid >> 2);
            *(uint4*)&Wcs[col * LDK + sc] = *(const uint4*)(Wct + (size_t)col * K + k0 + sc);
            *(uint4*)&Wds[col * LDK + sc] = *(const uint4*)(Wdt + (size_t)col * K + k0 + sc);
        }
        __syncthreads();
        bf16x8 aP[4], aX[4], bC[4], bD[4];
#pragma unroll
        for (int i = 0; i < 4; ++i) {
            aP[i] = *(bf16x8*)&Ps[(rh * 64 + 16 * i + m) * LDK + kh];
            aX[i] = *(bf16x8*)&Xs[(rh * 64 + 16 * i + m) * LDK + kh];
        }
#pragma unroll
        for (int j = 0; j < 4; ++j) {
            int c = cq * 64 + 16 * j + m;
            bC[j] = *(bf16x8*)&Wcs[c * LDK + kh];
            bD[j] = *(bf16x8*)&Wds[c * LDK + kh];
        }
#pragma unroll
        for (int i = 0; i < 4; ++i)
#pragma unroll
            for (int j = 0; j < 4; ++j) {
                accC[i][j] = __builtin_amdgcn_mfma_f32_16x16x32_bf16(aP[i], bC[j], accC[i][j], 0, 0, 0);
                accD[i][j] = __builtin_amdgcn_mfma_f32_16x16x32_bf16(aX[i], bD[j], accD[i][j], 0, 0, 0);
            }
        __syncthreads();
    }

    const int rq = (lane >> 4) * 4;
#pragma unroll
    for (int j = 0; j < 4; ++j) {
        int col = cq * 64 + 16 * j + m;
        float bcv = bc[col], bdv = bd[col];
#pragma unroll
        for (int i = 0; i < 4; ++i)
#pragma unroll
            for (int g = 0; g < 4; ++g) {
                int row = row0 + rh * 64 + 16 * i + rq + g;
                if (row < N) {
                    float v = fmaxf(accC[i][j][g] + bcv, 0.f) + accD[i][j][g] + bdv;
                    Out[(size_t)row * 256 + col] = f2bf(v);
                }
            }
    }
}

// ---------------- single-GEMM MFMA:  Out = [relu](A@W + b) ----------------
__global__ __launch_bounds__(256, 2) void k_gemm_mfma(
    const ushort* __restrict__ A, const ushort* __restrict__ Wt, const float* __restrict__ bias,
    ushort* __restrict__ Out, int N, int K, int M, int SA, int dorelu) {
    __shared__ short As[128 * LDK];
    __shared__ short Wls[256 * LDK];
    const int tid = threadIdx.x;
    const int wave = tid >> 6, lane = tid & 63;
    const int MW = M >> 6;
    const int R = 16384 / M;
    const int row0 = blockIdx.x * R;
    const int row_off = (wave / MW) * 64, col_off = (wave % MW) * 64;

    f32x4 acc[4][4];
#pragma unroll
    for (int i = 0; i < 4; ++i)
#pragma unroll
        for (int j = 0; j < 4; ++j) acc[i][j] = (f32x4)0.f;

    const int m = lane & 15, kh = (lane >> 4) * 8, sc = (tid & 3) * 8;

    for (int k0 = 0; k0 < K; k0 += 32) {
        for (int c = tid; c < R * 4; c += 256) {
            int r = c >> 2, ck = (c & 3) * 8;
            int gr = row0 + r; if (gr > N - 1) gr = N - 1;
            *(uint4*)&As[r * LDK + ck] = *(const uint4*)(A + (size_t)gr * SA + k0 + ck);
        }
        for (int p = 0; p < MW; ++p) {
            int col = p * 64 + (tid >> 2);
            *(uint4*)&Wls[col * LDK + sc] = *(const uint4*)(Wt + (size_t)col * K + k0 + sc);
        }
        __syncthreads();
        bf16x8 af[4], bf[4];
#pragma unroll
        for (int i = 0; i < 4; ++i) af[i] = *(bf16x8*)&As[(row_off + 16 * i + m) * LDK + kh];
#pragma unroll
        for (int j = 0; j < 4; ++j) bf[j] = *(bf16x8*)&Wls[(col_off + 16 * j + m) * LDK + kh];
#pragma unroll
        for (int i = 0; i < 4; ++i)
#pragma unroll
            for (int j = 0; j < 4; ++j)
                acc[i][j] = __builtin_amdgcn_mfma_f32_16x16x32_bf16(af[i], bf[j], acc[i][j], 0, 0, 0);
        __syncthreads();
    }

    const int rq = (lane >> 4) * 4;
#pragma unroll
    for (int j = 0; j < 4; ++j) {
        int col = col_off + 16 * j + m;
        float bv = bias[col];
#pragma unroll
        for (int i = 0; i < 4; ++i)
#pragma unroll
            for (int g = 0; g < 4; ++g) {
                int row = row0 + row_off + 16 * i + rq + g;
                if (row < N) {
                    float v = acc[i][j][g] + bv;
                    if (dorelu) v = fmaxf(v, 0.f);
                    Out[(size_t)row * M + col] = f2bf(v);
                }
            }
    }
}

// ---------------- pattern layer 2 + pooled epilogue (no pat materialization) ----------------
__global__ __launch_bounds__(256, 2) void k_pat2_pool(
    const ushort* __restrict__ A, const ushort* __restrict__ Wt, const float* __restrict__ bias,
    const int* __restrict__ batch, float* __restrict__ pesum, int N, int K, int SA) {
    __shared__ short As[64 * LDK];
    __shared__ short Wls[256 * LDK];
    __shared__ int sbatch[64];
    const int tid = threadIdx.x;
    const int wave = tid >> 6, lane = tid & 63;
    const int row0 = blockIdx.x * 64;
    const int col_off = wave * 64;

    f32x4 acc[4][4];
#pragma unroll
    for (int i = 0; i < 4; ++i)
#pragma unroll
        for (int j = 0; j < 4; ++j) acc[i][j] = (f32x4)0.f;

    const int m = lane & 15, kh = (lane >> 4) * 8, sc = (tid & 3) * 8;
    if (tid < 64) {
        int r = row0 + tid;
        sbatch[tid] = batch[r < N ? r : (N - 1)];
    }

    for (int k0 = 0; k0 < K; k0 += 32) {
        {
            int r = tid >> 2, ck = (tid & 3) * 8;
            int gr = row0 + r; if (gr > N - 1) gr = N - 1;
            *(uint4*)&As[r * LDK + ck] = *(const uint4*)(A + (size_t)gr * SA + k0 + ck);
        }
#pragma unroll
        for (int p = 0; p < 4; ++p) {
            int col = p * 64 + (tid >> 2);
            *(uint4*)&Wls[col * LDK + sc] = *(const uint4*)(Wt + (size_t)col * K + k0 + sc);
        }
        __syncthreads();
        bf16x8 af[4], bf[4];
#pragma unroll
        for (int i = 0; i < 4; ++i) af[i] = *(bf16x8*)&As[(16 * i + m) * LDK + kh];
#pragma unroll
        for (int j = 0; j < 4; ++j) bf[j] = *(bf16x8*)&Wls[(col_off + 16 * j + m) * LDK + kh];
#pragma unroll
        for (int i = 0; i < 4; ++i)
#pragma unroll
            for (int j = 0; j < 4; ++j)
                acc[i][j] = __builtin_amdgcn_mfma_f32_16x16x32_bf16(af[i], bf[j], acc[i][j], 0, 0, 0);
        __syncthreads();
    }

    const int rq = (lane >> 4) * 4;
    const int g0 = sbatch[0];
    const int g1 = sbatch[63];
    for (int g = g0; g <= g1; ++g) {
#pragma unroll
        for (int j = 0; j < 4; ++j) {
            float bv = bias[col_off + 16 * j + m];
            float s = 0.f;
#pragma unroll
            for (int i = 0; i < 4; ++i)
#pragma unroll
                for (int q = 0; q < 4; ++q) {
                    int rl = 16 * i + rq + q;
                    bool ok = (sbatch[rl] == g) && (row0 + rl < N);
                    float v = fmaxf(acc[i][j][q] + bv, 0.f);
                    s += ok ? v : 0.f;
                }
            s += __shfl_down(s, 32, 64);
            s += __shfl_down(s, 16, 64);
            if (lane < 16) atomicAdd(&pesum[(size_t)g * 256 + col_off + 16 * j + lane], s);
        }
    }
}

// ---------------- pooling ----------------
__global__ void k_ranges(const int* __restrict__ batch, int N, int B, int* __restrict__ start,
                         float* __restrict__ countsf) {
    int b = threadIdx.x;
    if (b <= B) {
        int lo = 0, hi = N;
        while (lo < hi) {
            int mid = (lo + hi) >> 1;
            if (batch[mid] < b) lo = mid + 1; else hi = mid;
        }
        start[b] = lo;
    }
    __syncthreads();
    if (b < B) {
        int cnt = start[b + 1] - start[b];
        countsf[b] = (float)(cnt > 0 ? cnt : 1);
    }
}

#define POOLS 16
__global__ __launch_bounds__(256) void k_pool2(const ushort* __restrict__ M_, const int* __restrict__ start,
                                               float* __restrict__ outsum) {
    int b = blockIdx.x;
    int s = blockIdx.y;
    int wave = threadIdx.x >> 6, lane = threadIdx.x & 63;
    int r0 = start[b], r1 = start[b + 1];
    int stripe = s * 4 + wave;
    float a0 = 0.f, a1 = 0.f, a2 = 0.f, a3 = 0.f;
    for (int r = r0 + stripe; r < r1; r += POOLS * 4) {
        ushort4 v = *(const ushort4*)(M_ + (size_t)r * 256 + lane * 4);
        a0 += b2f(v.x); a1 += b2f(v.y); a2 += b2f(v.z); a3 += b2f(v.w);
    }
    __shared__ float red[4][256];
    *(float4*)&red[wave][lane * 4] = make_float4(a0, a1, a2, a3);
    __syncthreads();
    int col = threadIdx.x;
    float t = red[0][col] + red[1][col] + red[2][col] + red[3][col];
    if (t != 0.f) atomicAdd(&outsum[(size_t)b * 256 + col], t);
}

// finalize pools + assemble comb in one pass
__global__ __launch_bounds__(256) void k_fin_comb(const float* __restrict__ gesum, const float* __restrict__ pesum,
                                                  const float* __restrict__ countsf,
                                                  const float* __restrict__ temb, const int* __restrict__ tidx,
                                                  float* __restrict__ comb) {
    int b = blockIdx.x, t = threadIdx.x;
    float inv = 1.0f / countsf[b];
    float* o = comb + (size_t)b * 1280;
    o[t] = gesum[(size_t)b * 256 + t] * inv;
    o[768 + t] = temb[(size_t)tidx[b] * 256 + t];
    o[1024 + t] = pesum[(size_t)b * 256 + t] * inv;
}

// ---------------- head: parallel fp32 dense layer ----------------
__global__ __launch_bounds__(256) void k_dense(const float* __restrict__ vin, int vs,
                                               const float* __restrict__ W, const float* __restrict__ bias,
                                               float* __restrict__ out, int os, int oo,
                                               int K, int M, int relu) {
    const int b = blockIdx.y;
    const int wave = threadIdx.x >> 6, lane = threadIdx.x & 63;
    const int c = blockIdx.x * 64 + lane;
    const float* vrow = vin + (size_t)b * vs;
    float acc = 0.f;
    int k = wave;
    for (; k + 28 < K; k += 32) {
#pragma unroll
        for (int u = 0; u < 8; ++u)
            acc += vrow[k + 4 * u] * W[(size_t)(k + 4 * u) * M + c];
    }
    for (; k < K; k += 4)
        acc += vrow[k] * W[(size_t)k * M + c];
    __shared__ float red[4][64];
    red[wave][lane] = acc;
    __syncthreads();
    if (wave == 0) {
        float s = red[0][lane] + red[1][lane] + red[2][lane] + red[3][lane] + bias[c];
        if (relu) s = fmaxf(s, 0.f);
        out[(size_t)b * os + oo + c] = s;
    }
}

__global__ __launch_bounds__(256) void k_heads_small(const float* __restrict__ fused,
                                                     const float* __restrict__ Wg, const float* __restrict__ bg,
                                                     const float* __restrict__ Wtp, const float* __restrict__ btp,
                                                     float* __restrict__ out_logits, float* __restrict__ out_tp,
                                                     int NG) {
    __shared__ float lf[256];
    int b = blockIdx.x, tid = threadIdx.x;
    int wave = tid >> 6, lane = tid & 63;
    lf[tid] = fused[(size_t)b * 256 + tid];
    __syncthreads();
    for (int c = wave; c < NG; c += 4) {
        float s = 0.f;
#pragma unroll
        for (int k = lane; k < 256; k += 64) s += lf[k] * Wg[(size_t)k * NG + c];
#pragma unroll
        for (int off = 32; off > 0; off >>= 1) s += __shfl_down(s, off, 64);
        if (lane == 0) out_logits[(size_t)b * NG + c] = s + bg[c];
    }
    if (wave == 0) {
        float s = 0.f;
#pragma unroll
        for (int k = lane; k < 256; k += 64) s += lf[k] * Wtp[k];
#pragma unroll
        for (int off = 32; off > 0; off >>= 1) s += __shfl_down(s, off, 64);
        if (lane == 0) out_tp[b] = s + btp[0];
    }
}

// ---------------- host launch ----------------
extern "C" void kernel_launch(void* const* d_in, const int* in_sizes, int n_in,
                              void* d_out, int out_size, void* d_ws, size_t ws_size,
                              hipStream_t stream) {
    const float* x   = (const float*)d_in[0];
    const int* ei    = (const int*)d_in[1];
    const int* batch = (const int*)d_in[2];
    const float* sf  = (const float*)d_in[3];
    const float* tf  = (const float*)d_in[4];
    const int* tidx  = (const int*)d_in[5];
    const float* temb = (const float*)d_in[6];
    const float *Ws1 = (const float*)d_in[7],  *bs1 = (const float*)d_in[8];
    const float *Ws2 = (const float*)d_in[9],  *bs2 = (const float*)d_in[10];
    const float *Wc1 = (const float*)d_in[11], *bc1 = (const float*)d_in[12];
    const float *Wc2 = (const float*)d_in[13], *bc2 = (const float*)d_in[14];
    const float *Wc3 = (const float*)d_in[15], *bc3 = (const float*)d_in[16];
    const float *Wd1 = (const float*)d_in[17], *bd1 = (const float*)d_in[18];
    const float *Wd2 = (const float*)d_in[19], *bd2 = (const float*)d_in[20];
    const float *Wd3 = (const float*)d_in[21], *bd3 = (const float*)d_in[22];
    const float *Wt1 = (const float*)d_in[23], *bt1 = (const float*)d_in[24];
    const float *Wt2 = (const float*)d_in[25], *bt2 = (const float*)d_in[26];
    const float *Wp1 = (const float*)d_in[27], *bp1 = (const float*)d_in[28];
    const float *Wp2 = (const float*)d_in[29], *bp2 = (const float*)d_in[30];
    const float *Wf1 = (const float*)d_in[31], *bf1 = (const float*)d_in[32];
    const float *Wf2 = (const float*)d_in[33], *bf2 = (const float*)d_in[34];
    const float *Wg  = (const float*)d_in[35], *bg  = (const float*)d_in[36];
    const float *Wtp = (const float*)d_in[37], *btp = (const float*)d_in[38];

    const int N = in_sizes[2];
    const int E = in_sizes[1] / 2;
    const int B = in_sizes[5];
    const int DIN = in_sizes[0] / N;       // 128
    const int DS = in_sizes[3] / B;        // 1024
    const int NG = in_sizes[36];           // 20
    const int* src = ei;
    const int* dst = ei + E;

    // ---- workspace layout ----
    char* w = (char*)d_ws;
    ushort* A   = (ushort*)w;              w += (size_t)N * 256 * 2;
    ushort* Bb  = (ushort*)w;              w += (size_t)N * 256 * 2;
    ushort* xh  = (ushort*)w;              w += (size_t)N * 128 * 2;
    ushort* Wc1t = (ushort*)w;             w += 128 * 256 * 2;
    ushort* Wd1t = (ushort*)w;             w += 128 * 256 * 2;
    ushort* Wc2t = (ushort*)w;             w += 256 * 256 * 2;
    ushort* Wd2t = (ushort*)w;             w += 256 * 256 * 2;
    ushort* Wc3t = (ushort*)w;             w += 256 * 256 * 2;
    ushort* Wd3t = (ushort*)w;             w += 256 * 256 * 2;
    ushort* Wp1t = (ushort*)w;             w += 256 * 128 * 2;
    ushort* Wp2t = (ushort*)w;             w += 128 * 256 * 2;
    int* esrc   = (int*)w;                 w += (size_t)E * 4;
    float* ewt  = (float*)w;               w += (size_t)E * 4;
    int* cnt    = (int*)w;                 w += (size_t)N * 4;
    int* part   = (int*)w;                 w += (size_t)N * 4;
    int* rowptr = (int*)w;                 w += (size_t)(N + 1) * 4;
    int* fill   = (int*)w;                 w += (size_t)N * 4;
    int* bsums  = (int*)w;                 w += 1024 * 4;
    float* dinv = (float*)w;               w += (size_t)N * 4;
    float* selfw = (float*)w;              w += (size_t)N * 4;
    int* startp = (int*)w;                 w += (B + 1) * 4;
    float* countsf = (float*)w;            w += B * 4;
    float* ge = (float*)w;                 w += B * 256 * 4;   // ge then pe contiguous (zeroed together)
    float* pe = (float*)w;                 w += B * 256 * 4;
    float* s1buf = (float*)w;              w += B * 256 * 4;
    float* t1buf = (float*)w;              w += B * 128 * 4;
    float* comb = (float*)w;               w += B * 1280 * 4;
    float* fh = (float*)w;                 w += B * 512 * 4;

    float* out_fused = (float*)d_out;                 // B x 256
    float* out_logits = out_fused + (size_t)B * H;    // B x NG
    float* out_tp = out_logits + (size_t)B * NG;      // B x 1

    dim3 blk(256);
    const int nbN = (N + 255) / 256;
    const int nbE = (E + 255) / 256;

    // ---- CSR build ----
    k_zero2_i<<<dim3(nbN), blk, 0, stream>>>(cnt, fill, N);
    k_count_deg_i<<<dim3(nbE), blk, 0, stream>>>(dst, cnt, E);
    k_scan1<<<dim3(nbN), blk, 0, stream>>>(cnt, part, bsums, N);
    k_scan2<<<dim3(1), dim3(1024), 0, stream>>>(bsums, nbN);
    k_scan3<<<dim3(nbN), blk, 0, stream>>>(part, bsums, cnt, rowptr, dinv, selfw, N);
    k_scatter<<<dim3(nbE), blk, 0, stream>>>(src, dst, dinv, rowptr, fill, esrc, ewt, E);

    // ---- batched conversions + pooling prep ----
    {
        long nx = (long)N * DIN;
        long tot = nx + 2L * DIN * 256 + 4L * 65536 + 2L * 32768;
        k_prep<<<dim3((unsigned)((tot + 255) / 256)), blk, 0, stream>>>(
            x, xh, nx, DIN, Wc1, Wc1t, Wd1, Wd1t, Wc2, Wc2t, Wd2, Wd2t,
            Wc3, Wc3t, Wd3, Wd3t, Wp1, Wp1t, Wp2, Wp2t);
        k_ranges<<<dim3(1), dim3(128), 0, stream>>>(batch, N, B, startp, countsf);
        k_zero_f<<<dim3((2 * B * 256 + 255) / 256), blk, 0, stream>>>(ge, 2 * B * 256);
    }

    const int ngb = (N + 3) / 4;
    const int nfb = (N + 127) / 128;

    // ---- static + temporal encoders ----
    k_dense<<<dim3(4, B), blk, 0, stream>>>(sf, DS, Ws1, bs1, s1buf, 256, 0, DS, 256, 1);
    k_dense<<<dim3(4, B), blk, 0, stream>>>(s1buf, 256, Ws2, bs2, comb, 1280, 256, 256, 256, 0);
    k_dense<<<dim3(2, B), blk, 0, stream>>>(tf, 5, Wt1, bt1, t1buf, 128, 0, 5, 128, 1);
    k_dense<<<dim3(4, B), blk, 0, stream>>>(t1buf, 128, Wt2, bt2, comb, 1280, 512, 128, 256, 0);

    // ---- 3 GCN layers ----
    k_gather_b2<<<dim3(ngb), blk, 0, stream>>>(xh, rowptr, esrc, ewt, selfw, A, N, 128, 128);
    k_fused_mfma<<<dim3(nfb), dim3(512), 0, stream>>>(A, xh, Wc1t, Wd1t, bc1, bd1, Bb, N, 128, 128, 128);
    k_gather_b4<<<dim3(ngb), blk, 0, stream>>>(Bb, rowptr, esrc, ewt, selfw, A, N, 256, 256);
    k_fused_mfma<<<dim3(nfb), dim3(512), 0, stream>>>(A, Bb, Wc2t, Wd2t, bc2, bd2, A, N, 256, 256, 256);
    k_gather_b4<<<dim3(ngb), blk, 0, stream>>>(A, rowptr, esrc, ewt, selfw, Bb, N, 256, 256);
    k_fused_mfma<<<dim3(nfb), dim3(512), 0, stream>>>(Bb, A, Wc3t, Wd3t, bc3, bd3, Bb, N, 256, 256, 256);

    // ---- ge = mean-pool(x3); pattern: p1 GEMM then fused pat+pool for pe ----
    k_pool2<<<dim3(B, POOLS), blk, 0, stream>>>(Bb, startp, ge);
    k_gemm_mfma<<<dim3((N + 127) / 128), blk, 0, stream>>>(Bb, Wp1t, bp1, A, N, 256, 128, 256, 1);
    k_pat2_pool<<<dim3((N + 63) / 64), blk, 0, stream>>>(A, Wp2t, bp2, batch, pe, N, 128, 128);
    k_fin_comb<<<dim3(B), blk, 0, stream>>>(ge, pe, countsf, temb, tidx, comb);

    // ---- head ----
    k_dense<<<dim3(8, B), blk, 0, stream>>>(comb, 1280, Wf1, bf1, fh, 512, 0, 1280, 512, 1);
    k_dense<<<dim3(4, B), blk, 0, stream>>>(fh, 512, Wf2, bf2, out_fused, 256, 0, 512, 256, 0);
    k_heads_small<<<dim3(B), blk, 0, stream>>>(out_fused, Wg, bg, Wtp, btp, out_logits, out_tp, NG);
}

// Round 9
// 856.502 us; speedup vs baseline: 1.6547x; 1.6547x over previous
//
#include <hip/hip_runtime.h>

#define H 256
#define LDK 40  // padded k-stride (halves): 80B rows -> <=2-way LDS bank aliasing (free)

typedef __attribute__((ext_vector_type(8))) short bf16x8;
typedef __attribute__((ext_vector_type(4))) float f32x4;

__device__ __forceinline__ float b2f(ushort h) {
    return __uint_as_float(((unsigned)h) << 16);
}
__device__ __forceinline__ ushort f2bf(float f) {
    unsigned u = __float_as_uint(f);
    unsigned r = (u + 0x7FFF + ((u >> 16) & 1)) >> 16;  // RNE
    return (ushort)r;
}

// ---------------- CSR build ----------------
__global__ __launch_bounds__(256) void k_zero2_i(int* p, int* q, int n) {
    int i = blockIdx.x * 256 + threadIdx.x;
    if (i < n) { p[i] = 0; q[i] = 0; }
}

__global__ __launch_bounds__(256) void k_zero_f(float* p, int n) {
    int i = blockIdx.x * 256 + threadIdx.x;
    if (i < n) p[i] = 0.f;
}

__global__ __launch_bounds__(256) void k_count_deg_i(const int* __restrict__ dst, int* cnt, int E) {
    int i = blockIdx.x * 256 + threadIdx.x;
    if (i < E) atomicAdd(&cnt[dst[i]], 1);
}

__global__ __launch_bounds__(256) void k_scan1(const int* __restrict__ cnt, int* __restrict__ partial,
                                               int* __restrict__ bsums, int N) {
    __shared__ int s[256];
    int t = threadIdx.x;
    int idx = blockIdx.x * 256 + t;
    int v = idx < N ? cnt[idx] : 0;
    s[t] = v;
    __syncthreads();
    for (int off = 1; off < 256; off <<= 1) {
        int add = (t >= off) ? s[t - off] : 0;
        __syncthreads();
        s[t] += add;
        __syncthreads();
    }
    if (idx < N) partial[idx] = s[t];
    if (t == 255) bsums[blockIdx.x] = s[t];
}

__global__ __launch_bounds__(1024) void k_scan2(int* bsums, int nb) {
    __shared__ int s[1024];
    int t = threadIdx.x;
    s[t] = (t < nb) ? bsums[t] : 0;
    __syncthreads();
    for (int off = 1; off < 1024; off <<= 1) {
        int add = (t >= off) ? s[t - off] : 0;
        __syncthreads();
        s[t] += add;
        __syncthreads();
    }
    if (t < nb) bsums[t] = s[t];
}

// rowptr + dinv/selfw in one pass
__global__ __launch_bounds__(256) void k_scan3(const int* __restrict__ partial, const int* __restrict__ bsums,
                                               const int* __restrict__ cnt,
                                               int* __restrict__ rowptr, float* __restrict__ dinv,
                                               float* __restrict__ selfw, int N) {
    int idx = blockIdx.x * 256 + threadIdx.x;
    if (idx < N) {
        int off = blockIdx.x > 0 ? bsums[blockIdx.x - 1] : 0;
        rowptr[idx + 1] = partial[idx] + off;
        if (idx == 0) rowptr[0] = 0;
        float d = 1.0f + (float)cnt[idx];
        dinv[idx] = rsqrtf(d);
        selfw[idx] = 1.0f / d;
    }
}

__global__ __launch_bounds__(256) void k_scatter(const int* __restrict__ src, const int* __restrict__ dst,
                                                 const float* __restrict__ dinv, const int* __restrict__ rowptr,
                                                 int* __restrict__ fill, int* __restrict__ esrc,
                                                 float* __restrict__ ewt, int E) {
    int e = blockIdx.x * 256 + threadIdx.x;
    if (e >= E) return;
    int s = src[e], d = dst[e];
    int pos = rowptr[d] + atomicAdd(&fill[d], 1);
    esrc[pos] = s;
    ewt[pos] = dinv[s] * dinv[d];
}

// ---------------- batched conversions: x->bf16 + all 8 weight transposes ----------------
__device__ __forceinline__ void tcvt_one(long i, const float* __restrict__ W, ushort* __restrict__ Wt,
                                         int K, int M) {
    int k = (int)(i / M), m = (int)(i - (long)k * M);
    Wt[(size_t)m * K + k] = f2bf(W[(size_t)k * M + m]);
}

__global__ __launch_bounds__(256) void k_prep(
    const float* __restrict__ x, ushort* __restrict__ xh, long nx, int DIN,
    const float* __restrict__ Wc1, ushort* Wc1t, const float* __restrict__ Wd1, ushort* Wd1t,
    const float* __restrict__ Wc2, ushort* Wc2t, const float* __restrict__ Wd2, ushort* Wd2t,
    const float* __restrict__ Wc3, ushort* Wc3t, const float* __restrict__ Wd3, ushort* Wd3t,
    const float* __restrict__ Wp1, ushort* Wp1t, const float* __restrict__ Wp2, ushort* Wp2t) {
    long i = (long)blockIdx.x * 256 + threadIdx.x;
    if (i < nx) { xh[i] = f2bf(x[i]); return; }
    i -= nx;
    long n1 = (long)DIN * 256;
    if (i < n1) { tcvt_one(i, Wc1, Wc1t, DIN, 256); return; }
    i -= n1;
    if (i < n1) { tcvt_one(i, Wd1, Wd1t, DIN, 256); return; }
    i -= n1;
    if (i < 65536) { tcvt_one(i, Wc2, Wc2t, 256, 256); return; }
    i -= 65536;
    if (i < 65536) { tcvt_one(i, Wd2, Wd2t, 256, 256); return; }
    i -= 65536;
    if (i < 65536) { tcvt_one(i, Wc3, Wc3t, 256, 256); return; }
    i -= 65536;
    if (i < 65536) { tcvt_one(i, Wd3, Wd3t, 256, 256); return; }
    i -= 65536;
    if (i < 32768) { tcvt_one(i, Wp1, Wp1t, 256, 128); return; }
    i -= 32768;
    if (i < 32768) { tcvt_one(i, Wp2, Wp2t, 128, 256); return; }
}

// ---------------- CSR gather (bf16 in, fp32 acc, bf16 out) ----------------
__global__ __launch_bounds__(256) void k_gather_b4(const ushort* __restrict__ xin, const int* __restrict__ rowptr,
                                                   const int* __restrict__ esrc, const float* __restrict__ ewt,
                                                   const float* __restrict__ selfw, ushort* __restrict__ p,
                                                   int N, int SX, int SP) {
    int node = blockIdx.x * 4 + (threadIdx.x >> 6);
    if (node >= N) return;
    int c = (threadIdx.x & 63) << 2;
    ushort4 h = *(const ushort4*)(xin + (size_t)node * SX + c);
    float sw = selfw[node];
    float a0 = b2f(h.x) * sw, a1 = b2f(h.y) * sw, a2 = b2f(h.z) * sw, a3 = b2f(h.w) * sw;
    int j = rowptr[node], r1 = rowptr[node + 1];
    for (; j + 3 < r1; j += 4) {
        int s0 = esrc[j], s1 = esrc[j + 1], s2 = esrc[j + 2], s3 = esrc[j + 3];
        float w0 = ewt[j], w1 = ewt[j + 1], w2 = ewt[j + 2], w3 = ewt[j + 3];
        ushort4 v0 = *(const ushort4*)(xin + (size_t)s0 * SX + c);
        ushort4 v1 = *(const ushort4*)(xin + (size_t)s1 * SX + c);
        ushort4 v2 = *(const ushort4*)(xin + (size_t)s2 * SX + c);
        ushort4 v3 = *(const ushort4*)(xin + (size_t)s3 * SX + c);
        a0 += b2f(v0.x) * w0 + b2f(v1.x) * w1 + b2f(v2.x) * w2 + b2f(v3.x) * w3;
        a1 += b2f(v0.y) * w0 + b2f(v1.y) * w1 + b2f(v2.y) * w2 + b2f(v3.y) * w3;
        a2 += b2f(v0.z) * w0 + b2f(v1.z) * w1 + b2f(v2.z) * w2 + b2f(v3.z) * w3;
        a3 += b2f(v0.w) * w0 + b2f(v1.w) * w1 + b2f(v2.w) * w2 + b2f(v3.w) * w3;
    }
    for (; j < r1; ++j) {
        int s0 = esrc[j];
        float w0 = ewt[j];
        ushort4 v0 = *(const ushort4*)(xin + (size_t)s0 * SX + c);
        a0 += b2f(v0.x) * w0; a1 += b2f(v0.y) * w0; a2 += b2f(v0.z) * w0; a3 += b2f(v0.w) * w0;
    }
    ushort4 o;
    o.x = f2bf(a0); o.y = f2bf(a1); o.z = f2bf(a2); o.w = f2bf(a3);
    *(ushort4*)(p + (size_t)node * SP + c) = o;
}

__global__ __launch_bounds__(256) void k_gather_b2(const ushort* __restrict__ xin, const int* __restrict__ rowptr,
                                                   const int* __restrict__ esrc, const float* __restrict__ ewt,
                                                   const float* __restrict__ selfw, ushort* __restrict__ p,
                                                   int N, int SX, int SP) {
    int node = blockIdx.x * 4 + (threadIdx.x >> 6);
    if (node >= N) return;
    int c = (threadIdx.x & 63) << 1;
    ushort2 h = *(const ushort2*)(xin + (size_t)node * SX + c);
    float sw = selfw[node];
    float a0 = b2f(h.x) * sw, a1 = b2f(h.y) * sw;
    int j = rowptr[node], r1 = rowptr[node + 1];
    for (; j + 3 < r1; j += 4) {
        int s0 = esrc[j], s1 = esrc[j + 1], s2 = esrc[j + 2], s3 = esrc[j + 3];
        float w0 = ewt[j], w1 = ewt[j + 1], w2 = ewt[j + 2], w3 = ewt[j + 3];
        ushort2 v0 = *(const ushort2*)(xin + (size_t)s0 * SX + c);
        ushort2 v1 = *(const ushort2*)(xin + (size_t)s1 * SX + c);
        ushort2 v2 = *(const ushort2*)(xin + (size_t)s2 * SX + c);
        ushort2 v3 = *(const ushort2*)(xin + (size_t)s3 * SX + c);
        a0 += b2f(v0.x) * w0 + b2f(v1.x) * w1 + b2f(v2.x) * w2 + b2f(v3.x) * w3;
        a1 += b2f(v0.y) * w0 + b2f(v1.y) * w1 + b2f(v2.y) * w2 + b2f(v3.y) * w3;
    }
    for (; j < r1; ++j) {
        int s0 = esrc[j];
        float w0 = ewt[j];
        ushort2 v0 = *(const ushort2*)(xin + (size_t)s0 * SX + c);
        a0 += b2f(v0.x) * w0; a1 += b2f(v0.y) * w0;
    }
    ushort2 o;
    o.x = f2bf(a0); o.y = f2bf(a1);
    *(ushort2*)(p + (size_t)node * SP + c) = o;
}

// ---------------- fused dual-GEMM MFMA:  Out = relu(Pm@Wc + bc) + X@Wd + bd ----------------
// 64 rows x 256 cols, 256 threads = 4 waves. NOTE: dual accumulators need 128 regs;
// do NOT constrain beyond 2 waves/EU or the compiler spills acc to scratch (round-8 regression).
__global__ __launch_bounds__(256, 2) void k_fused_mfma(
    const ushort* __restrict__ Pm, const ushort* __restrict__ X,
    const ushort* __restrict__ Wct, const ushort* __restrict__ Wdt,
    const float* __restrict__ bc, const float* __restrict__ bd,
    ushort* __restrict__ Out, int N, int K, int SP, int SX) {
    __shared__ short Ps[64 * LDK];
    __shared__ short Xs[64 * LDK];
    __shared__ short Wcs[256 * LDK];
    __shared__ short Wds[256 * LDK];
    const int tid = threadIdx.x;
    const int wave = tid >> 6, lane = tid & 63;
    const int row0 = blockIdx.x * 64;

    f32x4 accC[4][4], accD[4][4];
#pragma unroll
    for (int i = 0; i < 4; ++i)
#pragma unroll
        for (int j = 0; j < 4; ++j) { accC[i][j] = (f32x4)0.f; accD[i][j] = (f32x4)0.f; }

    const int sr = tid >> 2, sc = (tid & 3) * 8;
    int grow = row0 + sr; if (grow > N - 1) grow = N - 1;
    const int m = lane & 15, kh = (lane >> 4) * 8;

    for (int k0 = 0; k0 < K; k0 += 32) {
        *(uint4*)&Ps[sr * LDK + sc] = *(const uint4*)(Pm + (size_t)grow * SP + k0 + sc);
        *(uint4*)&Xs[sr * LDK + sc] = *(const uint4*)(X + (size_t)grow * SX + k0 + sc);
#pragma unroll
        for (int p = 0; p < 4; ++p) {
            int col = p * 64 + (tid >> 2);
            *(uint4*)&Wcs[col * LDK + sc] = *(const uint4*)(Wct + (size_t)col * K + k0 + sc);
            *(uint4*)&Wds[col * LDK + sc] = *(const uint4*)(Wdt + (size_t)col * K + k0 + sc);
        }
        __syncthreads();
        bf16x8 aP[4], aX[4], bC[4], bD[4];
#pragma unroll
        for (int i = 0; i < 4; ++i) {
            aP[i] = *(bf16x8*)&Ps[(16 * i + m) * LDK + kh];
            aX[i] = *(bf16x8*)&Xs[(16 * i + m) * LDK + kh];
        }
#pragma unroll
        for (int j = 0; j < 4; ++j) {
            int c = wave * 64 + 16 * j + m;
            bC[j] = *(bf16x8*)&Wcs[c * LDK + kh];
            bD[j] = *(bf16x8*)&Wds[c * LDK + kh];
        }
#pragma unroll
        for (int i = 0; i < 4; ++i)
#pragma unroll
            for (int j = 0; j < 4; ++j) {
                accC[i][j] = __builtin_amdgcn_mfma_f32_16x16x32_bf16(aP[i], bC[j], accC[i][j], 0, 0, 0);
                accD[i][j] = __builtin_amdgcn_mfma_f32_16x16x32_bf16(aX[i], bD[j], accD[i][j], 0, 0, 0);
            }
        __syncthreads();
    }

    const int rq = (lane >> 4) * 4;
#pragma unroll
    for (int j = 0; j < 4; ++j) {
        int col = wave * 64 + 16 * j + m;
        float bcv = bc[col], bdv = bd[col];
#pragma unroll
        for (int i = 0; i < 4; ++i)
#pragma unroll
            for (int g = 0; g < 4; ++g) {
                int row = row0 + 16 * i + rq + g;
                if (row < N) {
                    float v = fmaxf(accC[i][j][g] + bcv, 0.f) + accD[i][j][g] + bdv;
                    Out[(size_t)row * 256 + col] = f2bf(v);
                }
            }
    }
}

// ---------------- single-GEMM MFMA:  Out = [relu](A@W + b) ----------------
__global__ __launch_bounds__(256, 2) void k_gemm_mfma(
    const ushort* __restrict__ A, const ushort* __restrict__ Wt, const float* __restrict__ bias,
    ushort* __restrict__ Out, int N, int K, int M, int SA, int dorelu) {
    __shared__ short As[128 * LDK];
    __shared__ short Wls[256 * LDK];
    const int tid = threadIdx.x;
    const int wave = tid >> 6, lane = tid & 63;
    const int MW = M >> 6;
    const int R = 16384 / M;
    const int row0 = blockIdx.x * R;
    const int row_off = (wave / MW) * 64, col_off = (wave % MW) * 64;

    f32x4 acc[4][4];
#pragma unroll
    for (int i = 0; i < 4; ++i)
#pragma unroll
        for (int j = 0; j < 4; ++j) acc[i][j] = (f32x4)0.f;

    const int m = lane & 15, kh = (lane >> 4) * 8, sc = (tid & 3) * 8;

    for (int k0 = 0; k0 < K; k0 += 32) {
        for (int c = tid; c < R * 4; c += 256) {
            int r = c >> 2, ck = (c & 3) * 8;
            int gr = row0 + r; if (gr > N - 1) gr = N - 1;
            *(uint4*)&As[r * LDK + ck] = *(const uint4*)(A + (size_t)gr * SA + k0 + ck);
        }
        for (int p = 0; p < MW; ++p) {
            int col = p * 64 + (tid >> 2);
            *(uint4*)&Wls[col * LDK + sc] = *(const uint4*)(Wt + (size_t)col * K + k0 + sc);
        }
        __syncthreads();
        bf16x8 af[4], bf[4];
#pragma unroll
        for (int i = 0; i < 4; ++i) af[i] = *(bf16x8*)&As[(row_off + 16 * i + m) * LDK + kh];
#pragma unroll
        for (int j = 0; j < 4; ++j) bf[j] = *(bf16x8*)&Wls[(col_off + 16 * j + m) * LDK + kh];
#pragma unroll
        for (int i = 0; i < 4; ++i)
#pragma unroll
            for (int j = 0; j < 4; ++j)
                acc[i][j] = __builtin_amdgcn_mfma_f32_16x16x32_bf16(af[i], bf[j], acc[i][j], 0, 0, 0);
        __syncthreads();
    }

    const int rq = (lane >> 4) * 4;
#pragma unroll
    for (int j = 0; j < 4; ++j) {
        int col = col_off + 16 * j + m;
        float bv = bias[col];
#pragma unroll
        for (int i = 0; i < 4; ++i)
#pragma unroll
            for (int g = 0; g < 4; ++g) {
                int row = row0 + row_off + 16 * i + rq + g;
                if (row < N) {
                    float v = acc[i][j][g] + bv;
                    if (dorelu) v = fmaxf(v, 0.f);
                    Out[(size_t)row * M + col] = f2bf(v);
                }
            }
    }
}

// ---------------- pattern layer 2 + pooled epilogue (no pat materialization) ----------------
__global__ __launch_bounds__(256, 2) void k_pat2_pool(
    const ushort* __restrict__ A, const ushort* __restrict__ Wt, const float* __restrict__ bias,
    const int* __restrict__ batch, float* __restrict__ pesum, int N, int K, int SA) {
    __shared__ short As[64 * LDK];
    __shared__ short Wls[256 * LDK];
    __shared__ int sbatch[64];
    const int tid = threadIdx.x;
    const int wave = tid >> 6, lane = tid & 63;
    const int row0 = blockIdx.x * 64;
    const int col_off = wave * 64;

    f32x4 acc[4][4];
#pragma unroll
    for (int i = 0; i < 4; ++i)
#pragma unroll
        for (int j = 0; j < 4; ++j) acc[i][j] = (f32x4)0.f;

    const int m = lane & 15, kh = (lane >> 4) * 8, sc = (tid & 3) * 8;
    if (tid < 64) {
        int r = row0 + tid;
        sbatch[tid] = batch[r < N ? r : (N - 1)];
    }

    for (int k0 = 0; k0 < K; k0 += 32) {
        {
            int r = tid >> 2, ck = (tid & 3) * 8;
            int gr = row0 + r; if (gr > N - 1) gr = N - 1;
            *(uint4*)&As[r * LDK + ck] = *(const uint4*)(A + (size_t)gr * SA + k0 + ck);
        }
#pragma unroll
        for (int p = 0; p < 4; ++p) {
            int col = p * 64 + (tid >> 2);
            *(uint4*)&Wls[col * LDK + sc] = *(const uint4*)(Wt + (size_t)col * K + k0 + sc);
        }
        __syncthreads();
        bf16x8 af[4], bf[4];
#pragma unroll
        for (int i = 0; i < 4; ++i) af[i] = *(bf16x8*)&As[(16 * i + m) * LDK + kh];
#pragma unroll
        for (int j = 0; j < 4; ++j) bf[j] = *(bf16x8*)&Wls[(col_off + 16 * j + m) * LDK + kh];
#pragma unroll
        for (int i = 0; i < 4; ++i)
#pragma unroll
            for (int j = 0; j < 4; ++j)
                acc[i][j] = __builtin_amdgcn_mfma_f32_16x16x32_bf16(af[i], bf[j], acc[i][j], 0, 0, 0);
        __syncthreads();
    }

    const int rq = (lane >> 4) * 4;
    const int g0 = sbatch[0];
    const int g1 = sbatch[63];
    for (int g = g0; g <= g1; ++g) {
#pragma unroll
        for (int j = 0; j < 4; ++j) {
            float bv = bias[col_off + 16 * j + m];
            float s = 0.f;
#pragma unroll
            for (int i = 0; i < 4; ++i)
#pragma unroll
                for (int q = 0; q < 4; ++q) {
                    int rl = 16 * i + rq + q;
                    bool ok = (sbatch[rl] == g) && (row0 + rl < N);
                    float v = fmaxf(acc[i][j][q] + bv, 0.f);
                    s += ok ? v : 0.f;
                }
            s += __shfl_down(s, 32, 64);
            s += __shfl_down(s, 16, 64);
            if (lane < 16) atomicAdd(&pesum[(size_t)g * 256 + col_off + 16 * j + lane], s);
        }
    }
}

// ---------------- pooling ----------------
__global__ void k_ranges(const int* __restrict__ batch, int N, int B, int* __restrict__ start,
                         float* __restrict__ countsf) {
    int b = threadIdx.x;
    if (b <= B) {
        int lo = 0, hi = N;
        while (lo < hi) {
            int mid = (lo + hi) >> 1;
            if (batch[mid] < b) lo = mid + 1; else hi = mid;
        }
        start[b] = lo;
    }
    __syncthreads();
    if (b < B) {
        int cnt = start[b + 1] - start[b];
        countsf[b] = (float)(cnt > 0 ? cnt : 1);
    }
}

#define POOLS 16
__global__ __launch_bounds__(256) void k_pool2(const ushort* __restrict__ M_, const int* __restrict__ start,
                                               float* __restrict__ outsum) {
    int b = blockIdx.x;
    int s = blockIdx.y;
    int wave = threadIdx.x >> 6, lane = threadIdx.x & 63;
    int r0 = start[b], r1 = start[b + 1];
    int stripe = s * 4 + wave;
    float a0 = 0.f, a1 = 0.f, a2 = 0.f, a3 = 0.f;
    for (int r = r0 + stripe; r < r1; r += POOLS * 4) {
        ushort4 v = *(const ushort4*)(M_ + (size_t)r * 256 + lane * 4);
        a0 += b2f(v.x); a1 += b2f(v.y); a2 += b2f(v.z); a3 += b2f(v.w);
    }
    __shared__ float red[4][256];
    *(float4*)&red[wave][lane * 4] = make_float4(a0, a1, a2, a3);
    __syncthreads();
    int col = threadIdx.x;
    float t = red[0][col] + red[1][col] + red[2][col] + red[3][col];
    if (t != 0.f) atomicAdd(&outsum[(size_t)b * 256 + col], t);
}

// finalize pools + assemble comb in one pass
__global__ __launch_bounds__(256) void k_fin_comb(const float* __restrict__ gesum, const float* __restrict__ pesum,
                                                  const float* __restrict__ countsf,
                                                  const float* __restrict__ temb, const int* __restrict__ tidx,
                                                  float* __restrict__ comb) {
    int b = blockIdx.x, t = threadIdx.x;
    float inv = 1.0f / countsf[b];
    float* o = comb + (size_t)b * 1280;
    o[t] = gesum[(size_t)b * 256 + t] * inv;
    o[768 + t] = temb[(size_t)tidx[b] * 256 + t];
    o[1024 + t] = pesum[(size_t)b * 256 + t] * inv;
}

// ---------------- head: parallel fp32 dense layer ----------------
__global__ __launch_bounds__(256) void k_dense(const float* __restrict__ vin, int vs,
                                               const float* __restrict__ W, const float* __restrict__ bias,
                                               float* __restrict__ out, int os, int oo,
                                               int K, int M, int relu) {
    const int b = blockIdx.y;
    const int wave = threadIdx.x >> 6, lane = threadIdx.x & 63;
    const int c = blockIdx.x * 64 + lane;
    const float* vrow = vin + (size_t)b * vs;
    float acc = 0.f;
    int k = wave;
    for (; k + 28 < K; k += 32) {
#pragma unroll
        for (int u = 0; u < 8; ++u)
            acc += vrow[k + 4 * u] * W[(size_t)(k + 4 * u) * M + c];
    }
    for (; k < K; k += 4)
        acc += vrow[k] * W[(size_t)k * M + c];
    __shared__ float red[4][64];
    red[wave][lane] = acc;
    __syncthreads();
    if (wave == 0) {
        float s = red[0][lane] + red[1][lane] + red[2][lane] + red[3][lane] + bias[c];
        if (relu) s = fmaxf(s, 0.f);
        out[(size_t)b * os + oo + c] = s;
    }
}

__global__ __launch_bounds__(256) void k_heads_small(const float* __restrict__ fused,
                                                     const float* __restrict__ Wg, const float* __restrict__ bg,
                                                     const float* __restrict__ Wtp, const float* __restrict__ btp,
                                                     float* __restrict__ out_logits, float* __restrict__ out_tp,
                                                     int NG) {
    __shared__ float lf[256];
    int b = blockIdx.x, tid = threadIdx.x;
    int wave = tid >> 6, lane = tid & 63;
    lf[tid] = fused[(size_t)b * 256 + tid];
    __syncthreads();
    for (int c = wave; c < NG; c += 4) {
        float s = 0.f;
#pragma unroll
        for (int k = lane; k < 256; k += 64) s += lf[k] * Wg[(size_t)k * NG + c];
#pragma unroll
        for (int off = 32; off > 0; off >>= 1) s += __shfl_down(s, off, 64);
        if (lane == 0) out_logits[(size_t)b * NG + c] = s + bg[c];
    }
    if (wave == 0) {
        float s = 0.f;
#pragma unroll
        for (int k = lane; k < 256; k += 64) s += lf[k] * Wtp[k];
#pragma unroll
        for (int off = 32; off > 0; off >>= 1) s += __shfl_down(s, off, 64);
        if (lane == 0) out_tp[b] = s + btp[0];
    }
}

// ---------------- host launch ----------------
extern "C" void kernel_launch(void* const* d_in, const int* in_sizes, int n_in,
                              void* d_out, int out_size, void* d_ws, size_t ws_size,
                              hipStream_t stream) {
    const float* x   = (const float*)d_in[0];
    const int* ei    = (const int*)d_in[1];
    const int* batch = (const int*)d_in[2];
    const float* sf  = (const float*)d_in[3];
    const float* tf  = (const float*)d_in[4];
    const int* tidx  = (const int*)d_in[5];
    const float* temb = (const float*)d_in[6];
    const float *Ws1 = (const float*)d_in[7],  *bs1 = (const float*)d_in[8];
    const float *Ws2 = (const float*)d_in[9],  *bs2 = (const float*)d_in[10];
    const float *Wc1 = (const float*)d_in[11], *bc1 = (const float*)d_in[12];
    const float *Wc2 = (const float*)d_in[13], *bc2 = (const float*)d_in[14];
    const float *Wc3 = (const float*)d_in[15], *bc3 = (const float*)d_in[16];
    const float *Wd1 = (const float*)d_in[17], *bd1 = (const float*)d_in[18];
    const float *Wd2 = (const float*)d_in[19], *bd2 = (const float*)d_in[20];
    const float *Wd3 = (const float*)d_in[21], *bd3 = (const float*)d_in[22];
    const float *Wt1 = (const float*)d_in[23], *bt1 = (const float*)d_in[24];
    const float *Wt2 = (const float*)d_in[25], *bt2 = (const float*)d_in[26];
    const float *Wp1 = (const float*)d_in[27], *bp1 = (const float*)d_in[28];
    const float *Wp2 = (const float*)d_in[29], *bp2 = (const float*)d_in[30];
    const float *Wf1 = (const float*)d_in[31], *bf1 = (const float*)d_in[32];
    const float *Wf2 = (const float*)d_in[33], *bf2 = (const float*)d_in[34];
    const float *Wg  = (const float*)d_in[35], *bg  = (const float*)d_in[36];
    const float *Wtp = (const float*)d_in[37], *btp = (const float*)d_in[38];

    const int N = in_sizes[2];
    const int E = in_sizes[1] / 2;
    const int B = in_sizes[5];
    const int DIN = in_sizes[0] / N;       // 128
    const int DS = in_sizes[3] / B;        // 1024
    const int NG = in_sizes[36];           // 20
    const int* src = ei;
    const int* dst = ei + E;

    // ---- workspace layout ----
    char* w = (char*)d_ws;
    ushort* A   = (ushort*)w;              w += (size_t)N * 256 * 2;
    ushort* Bb  = (ushort*)w;              w += (size_t)N * 256 * 2;
    ushort* xh  = (ushort*)w;              w += (size_t)N * 128 * 2;
    ushort* Wc1t = (ushort*)w;             w += 128 * 256 * 2;
    ushort* Wd1t = (ushort*)w;             w += 128 * 256 * 2;
    ushort* Wc2t = (ushort*)w;             w += 256 * 256 * 2;
    ushort* Wd2t = (ushort*)w;             w += 256 * 256 * 2;
    ushort* Wc3t = (ushort*)w;             w += 256 * 256 * 2;
    ushort* Wd3t = (ushort*)w;             w += 256 * 256 * 2;
    ushort* Wp1t = (ushort*)w;             w += 256 * 128 * 2;
    ushort* Wp2t = (ushort*)w;             w += 128 * 256 * 2;
    int* esrc   = (int*)w;                 w += (size_t)E * 4;
    float* ewt  = (float*)w;               w += (size_t)E * 4;
    int* cnt    = (int*)w;                 w += (size_t)N * 4;
    int* part   = (int*)w;                 w += (size_t)N * 4;
    int* rowptr = (int*)w;                 w += (size_t)(N + 1) * 4;
    int* fill   = (int*)w;                 w += (size_t)N * 4;
    int* bsums  = (int*)w;                 w += 1024 * 4;
    float* dinv = (float*)w;               w += (size_t)N * 4;
    float* selfw = (float*)w;              w += (size_t)N * 4;
    int* startp = (int*)w;                 w += (B + 1) * 4;
    float* countsf = (float*)w;            w += B * 4;
    float* ge = (float*)w;                 w += B * 256 * 4;   // ge then pe contiguous (zeroed together)
    float* pe = (float*)w;                 w += B * 256 * 4;
    float* s1buf = (float*)w;              w += B * 256 * 4;
    float* t1buf = (float*)w;              w += B * 128 * 4;
    float* comb = (float*)w;               w += B * 1280 * 4;
    float* fh = (float*)w;                 w += B * 512 * 4;

    float* out_fused = (float*)d_out;                 // B x 256
    float* out_logits = out_fused + (size_t)B * H;    // B x NG
    float* out_tp = out_logits + (size_t)B * NG;      // B x 1

    dim3 blk(256);
    const int nbN = (N + 255) / 256;
    const int nbE = (E + 255) / 256;

    // ---- CSR build ----
    k_zero2_i<<<dim3(nbN), blk, 0, stream>>>(cnt, fill, N);
    k_count_deg_i<<<dim3(nbE), blk, 0, stream>>>(dst, cnt, E);
    k_scan1<<<dim3(nbN), blk, 0, stream>>>(cnt, part, bsums, N);
    k_scan2<<<dim3(1), dim3(1024), 0, stream>>>(bsums, nbN);
    k_scan3<<<dim3(nbN), blk, 0, stream>>>(part, bsums, cnt, rowptr, dinv, selfw, N);
    k_scatter<<<dim3(nbE), blk, 0, stream>>>(src, dst, dinv, rowptr, fill, esrc, ewt, E);

    // ---- batched conversions + pooling prep ----
    {
        long nx = (long)N * DIN;
        long tot = nx + 2L * DIN * 256 + 4L * 65536 + 2L * 32768;
        k_prep<<<dim3((unsigned)((tot + 255) / 256)), blk, 0, stream>>>(
            x, xh, nx, DIN, Wc1, Wc1t, Wd1, Wd1t, Wc2, Wc2t, Wd2, Wd2t,
            Wc3, Wc3t, Wd3, Wd3t, Wp1, Wp1t, Wp2, Wp2t);
        k_ranges<<<dim3(1), dim3(128), 0, stream>>>(batch, N, B, startp, countsf);
        k_zero_f<<<dim3((2 * B * 256 + 255) / 256), blk, 0, stream>>>(ge, 2 * B * 256);
    }

    const int ngb = (N + 3) / 4;
    const int nfb = (N + 63) / 64;

    // ---- static + temporal encoders ----
    k_dense<<<dim3(4, B), blk, 0, stream>>>(sf, DS, Ws1, bs1, s1buf, 256, 0, DS, 256, 1);
    k_dense<<<dim3(4, B), blk, 0, stream>>>(s1buf, 256, Ws2, bs2, comb, 1280, 256, 256, 256, 0);
    k_dense<<<dim3(2, B), blk, 0, stream>>>(tf, 5, Wt1, bt1, t1buf, 128, 0, 5, 128, 1);
    k_dense<<<dim3(4, B), blk, 0, stream>>>(t1buf, 128, Wt2, bt2, comb, 1280, 512, 128, 256, 0);

    // ---- 3 GCN layers ----
    k_gather_b2<<<dim3(ngb), blk, 0, stream>>>(xh, rowptr, esrc, ewt, selfw, A, N, 128, 128);
    k_fused_mfma<<<dim3(nfb), blk, 0, stream>>>(A, xh, Wc1t, Wd1t, bc1, bd1, Bb, N, 128, 128, 128);
    k_gather_b4<<<dim3(ngb), blk, 0, stream>>>(Bb, rowptr, esrc, ewt, selfw, A, N, 256, 256);
    k_fused_mfma<<<dim3(nfb), blk, 0, stream>>>(A, Bb, Wc2t, Wd2t, bc2, bd2, A, N, 256, 256, 256);
    k_gather_b4<<<dim3(ngb), blk, 0, stream>>>(A, rowptr, esrc, ewt, selfw, Bb, N, 256, 256);
    k_fused_mfma<<<dim3(nfb), blk, 0, stream>>>(Bb, A, Wc3t, Wd3t, bc3, bd3, Bb, N, 256, 256, 256);

    // ---- ge = mean-pool(x3); pattern: p1 GEMM then fused pat+pool for pe ----
    k_pool2<<<dim3(B, POOLS), blk, 0, stream>>>(Bb, startp, ge);
    k_gemm_mfma<<<dim3((N + 127) / 128), blk, 0, stream>>>(Bb, Wp1t, bp1, A, N, 256, 128, 256, 1);
    k_pat2_pool<<<dim3((N + 63) / 64), blk, 0, stream>>>(A, Wp2t, bp2, batch, pe, N, 128, 128);
    k_fin_comb<<<dim3(B), blk, 0, stream>>>(ge, pe, countsf, temb, tidx, comb);

    // ---- head ----
    k_dense<<<dim3(8, B), blk, 0, stream>>>(comb, 1280, Wf1, bf1, fh, 512, 0, 1280, 512, 1);
    k_dense<<<dim3(4, B), blk, 0, stream>>>(fh, 512, Wf2, bf2, out_fused, 256, 0, 512, 256, 0);
    k_heads_small<<<dim3(B), blk, 0, stream>>>(out_fused, Wg, bg, Wtp, btp, out_logits, out_tp, NG);
}